// Round 7
// baseline (97.199 us; speedup 1.0000x reference)
//
#include <hip/hip_runtime.h>
#include <math.h>

// PLIF (parametric LIF) forward, heterogeneous per-feature decay/threshold.
// x: [B=4, N=1024, T=128, D=128] fp32, sequential scan over T per (b,n,d):
//   v = v * sigmoid(decay[d]) + x[t]
//   s = (v > sigmoid(v_th[d]) + 0.1) ? 1 : 0
//   v = s ? 0 : v        (hard reset; exact since s in {0,1})
//
// R7: R6 (LDS-staged wide I/O, 94.4us = 90.5% of copy ceiling) with:
//   - in-place spike buffer: compute writes the spike back into the xs slot
//     it just read (same thread owns both; cross-thread accesses fenced by
//     the two barriers; back-edge store-read -> stage-write is same-thread
//     same-address, ordered by the per-wave LDS pipe). Halves LDS.
//   - CT 8 -> 16: 16KB/block, still 8 blocks/CU (128KB <= 160KB LDS), full
//     32 waves/CU. Halves the barrier count (32 -> 16): hipcc drains
//     vmcnt(0) before every s_barrier, pulling NT stores + stage loads into
//     the critical path once per barrier -- the remaining per-chunk cost.
//
// __fmul_rn/__fadd_rn prevent fma contraction so fp32 rounding matches the
// mul-then-add numpy reference exactly (spike compares are boundary-
// sensitive: one ulp flip -> absmax 1.0). R1/R3-R6 passed absmax 0.0.

#define T_STEPS 128
#define D_FEAT  128
#define CT      16                // time-steps per staged chunk
#define CTD     (CT * D_FEAT)     // 2048 floats per row-chunk
#define NCHUNK  (T_STEPS / CT)    // 8 chunks

typedef float f32x4 __attribute__((ext_vector_type(4)));

__global__ __launch_bounds__(256)
void plif_fwd_kernel(const f32x4* __restrict__ x4,
                     const float* __restrict__ decay,
                     const float* __restrict__ vth,
                     f32x4* __restrict__ out4)
{
    __shared__ float xs[2 * CTD];           // 16 KB: [2 rows][CT][D], reused for spikes

    const int tid  = threadIdx.x;
    const int lrow = tid >> 7;              // 0/1: which of the block's rows
    const int d    = tid & (D_FEAT - 1);    // feature index
    const int r0   = blockIdx.x * 2;        // first row of this block

    // per-feature constants (2 expf per thread -- negligible)
    const float dec = 1.0f / (1.0f + expf(-decay[d]));
    const float th  = 1.0f / (1.0f + expf(-vth[d])) + 0.1f;

    const size_t rowq = (size_t)T_STEPS * D_FEAT / 4;   // float4s per row

    float v = 0.0f;

    for (int c = 0; c < NCHUNK; ++c) {
        const size_t cq = (size_t)c * (CTD / 4);        // float4 offset in row

        // ---- stage x: 4 rounds of fully-contiguous 4KB float4 loads ----
#pragma unroll
        for (int p = 0; p < 4; ++p) {
            const int rr   = p >> 1;        // which row
            const int slot = (p & 1) * 256 + tid;
            const f32x4 tmp = __builtin_nontemporal_load(
                x4 + (size_t)(r0 + rr) * rowq + cq + (size_t)slot);
            *(f32x4*)&xs[rr * CTD + slot * 4] = tmp;
        }
        __syncthreads();

        // ---- compute CT steps of this thread's (row, d) chain, spike
        //      written back in-place (same thread read+write, barrier-fenced
        //      against all cross-thread access) ----
#pragma unroll
        for (int i = 0; i < CT; ++i) {
            const int idx = lrow * CTD + i * D_FEAT + d;
            const float xv = xs[idx];
            v = __fadd_rn(__fmul_rn(v, dec), xv);
            const bool f = (v > th);
            xs[idx] = f ? 1.0f : 0.0f;
            v = f ? 0.0f : v;
        }
        __syncthreads();

        // ---- store spikes: 4 rounds of contiguous float4 stores ----
        // (no trailing barrier: next stage writes exactly the slots this
        //  thread reads here, same-thread ordering in the LDS pipe)
#pragma unroll
        for (int p = 0; p < 4; ++p) {
            const int rr   = p >> 1;
            const int slot = (p & 1) * 256 + tid;
            const f32x4 sv = *(const f32x4*)&xs[rr * CTD + slot * 4];
            __builtin_nontemporal_store(sv,
                out4 + (size_t)(r0 + rr) * rowq + cq + (size_t)slot);
        }
    }
}

extern "C" void kernel_launch(void* const* d_in, const int* in_sizes, int n_in,
                              void* d_out, int out_size, void* d_ws, size_t ws_size,
                              hipStream_t stream)
{
    const float* x     = (const float*)d_in[0];
    const float* decay = (const float*)d_in[1];
    const float* vth   = (const float*)d_in[2];
    float*       out   = (float*)d_out;

    const int total  = in_sizes[0];                    // B*N*T*D = 67108864
    const int rows   = total / (T_STEPS * D_FEAT);     // B*N = 4096
    const int blocks = rows / 2;                       // 2048
    const int block  = 256;

    plif_fwd_kernel<<<blocks, block, 0, stream>>>(
        (const f32x4*)x, decay, vth, (f32x4*)out);
}